// Round 7
// baseline (239.207 us; speedup 1.0000x reference)
//
#include <hip/hip_runtime.h>
#include <stdint.h>

typedef __bf16 bf16_t;
typedef __bf16 bf16x8 __attribute__((ext_vector_type(8)));
typedef __bf16 bf16x4 __attribute__((ext_vector_type(4)));
typedef float  f32x4  __attribute__((ext_vector_type(4)));

#define AS1 __attribute__((address_space(1)))
#define AS3 __attribute__((address_space(3)))

#define SEQ   4096
#define DIMM  512
#define DIN   1024
#define ROWS  16384   // BATCH*SEQLEN

__device__ __forceinline__ void gload_lds16(const void* g, void* l) {
  __builtin_amdgcn_global_load_lds((AS1 void*)g, (AS3 void*)l, 16, 0, 0);
}

// ================= GEMM1: 256x256 tile, BK=32, 4-deep LDS ring, counted vmcnt =================
// C = A (MxK, lda) * B^T (NxK, ldb), bf16 in, bf16 out. 512 threads = 8 waves (2M x 4N),
// per-wave output 128x64. 2 phases per K-tile (16 MFMA each), stage 2 K-tiles ahead,
// one raw s_barrier + vmcnt(4) per K-tile (never drains mid-loop). K%32==0, M%256==0, N%256==0.
__global__ __launch_bounds__(512, 2) void gemm8(
    const bf16_t* __restrict__ A, const bf16_t* __restrict__ B,
    bf16_t* __restrict__ C, int lda, int ldb, int N, int K)
{
  __shared__ __align__(16) bf16_t Abuf[4][256*32];
  __shared__ __align__(16) bf16_t Bbuf[4][256*32];
  const int tid = threadIdx.x;
  const int l = tid & 63, w = tid >> 6;
  const int wr = w >> 2, wc = w & 3;          // wave's M-half / N-quarter
  const int lr = l & 15, g = l >> 4;          // frag row lane, k-granule
  const int bm = blockIdx.x, bn = blockIdx.y;
  const int NT = K >> 5;

  // staging: load j covers granule gid = j*512 + tid; row = gid>>2, col = (gid&3)*8
  const int r0 = tid >> 2, c0e = (tid & 3) * 8;
  const bf16_t* As0 = A + (size_t)(bm*256 +       r0)*lda + c0e;
  const bf16_t* As1 = A + (size_t)(bm*256 + 128 + r0)*lda + c0e;
  const bf16_t* Bs0 = B + (size_t)(bn*256 +       r0)*ldb + c0e;
  const bf16_t* Bs1 = B + (size_t)(bn*256 + 128 + r0)*ldb + c0e;

  f32x4 acc[8][4] = {};

#define STAGE_A(kt_) { int d_ = (kt_) & 3; size_t ko_ = (size_t)(kt_)*32; \
    gload_lds16(As0 + ko_, &Abuf[d_][w*512]); \
    gload_lds16(As1 + ko_, &Abuf[d_][4096 + w*512]); }
#define STAGE_B(kt_) { int d_ = (kt_) & 3; size_t ko_ = (size_t)(kt_)*32; \
    gload_lds16(Bs0 + ko_, &Bbuf[d_][w*512]); \
    gload_lds16(Bs1 + ko_, &Bbuf[d_][4096 + w*512]); }

  // prologue: stage kt0, kt1; wait for kt0 (oldest 4 of 8)
  STAGE_A(0); STAGE_B(0);
  STAGE_A(1); STAGE_B(1);
  asm volatile("s_waitcnt vmcnt(4)" ::: "memory");
  __builtin_amdgcn_s_barrier();
  __builtin_amdgcn_sched_barrier(0);

  const int arow = wr*128 + lr;   // + m*16 (+64 for phase 2)
  const int brow = wc*64  + lr;   // + n*16

  for (int kt = 0; kt < NT; ++kt) {
    const bf16_t* Ab = Abuf[kt & 3];
    const bf16_t* Bb = Bbuf[kt & 3];
    bf16x8 av[4], bv[4];
    // ---- phase 1: rows 0..63 of wave's half ----
#pragma unroll
    for (int m = 0; m < 4; m++) av[m] = *(const bf16x8*)&Ab[(arow + m*16)*32 + g*8];
#pragma unroll
    for (int n = 0; n < 4; n++) bv[n] = *(const bf16x8*)&Bb[(brow + n*16)*32 + g*8];
    if (kt + 2 < NT) STAGE_A(kt + 2);
    asm volatile("s_waitcnt lgkmcnt(0)" ::: "memory");
    __builtin_amdgcn_sched_barrier(0);
    __builtin_amdgcn_s_setprio(1);
#pragma unroll
    for (int m = 0; m < 4; m++)
#pragma unroll
      for (int n = 0; n < 4; n++)
        acc[m][n] = __builtin_amdgcn_mfma_f32_16x16x32_bf16(av[m], bv[n], acc[m][n], 0, 0, 0);
    __builtin_amdgcn_s_setprio(0);
    __builtin_amdgcn_sched_barrier(0);
    // ---- phase 2: rows 64..127 (B frags reused from registers) ----
#pragma unroll
    for (int m = 0; m < 4; m++) av[m] = *(const bf16x8*)&Ab[(arow + 64 + m*16)*32 + g*8];
    if (kt + 2 < NT) STAGE_B(kt + 2);
    asm volatile("s_waitcnt lgkmcnt(0)" ::: "memory");
    __builtin_amdgcn_sched_barrier(0);
    __builtin_amdgcn_s_setprio(1);
#pragma unroll
    for (int m = 0; m < 4; m++)
#pragma unroll
      for (int n = 0; n < 4; n++)
        acc[4+m][n] = __builtin_amdgcn_mfma_f32_16x16x32_bf16(av[m], bv[n], acc[4+m][n], 0, 0, 0);
    __builtin_amdgcn_s_setprio(0);
    __builtin_amdgcn_sched_barrier(0);
    // ---- K-tile boundary: counted wait for next tile's 4 loads, then barrier ----
    if (kt < NT - 1) {
      if (kt + 2 < NT) asm volatile("s_waitcnt vmcnt(4)" ::: "memory");
      else             asm volatile("s_waitcnt vmcnt(0)" ::: "memory");
      __builtin_amdgcn_s_barrier();
      __builtin_amdgcn_sched_barrier(0);
    }
  }
#undef STAGE_A
#undef STAGE_B

  const int row0 = bm*256 + wr*128 + g*4;
  const int col0 = bn*256 + wc*64 + lr;
#pragma unroll
  for (int m = 0; m < 8; m++)
#pragma unroll
    for (int n = 0; n < 4; n++)
#pragma unroll
      for (int r = 0; r < 4; r++)
        C[(size_t)(row0 + m*16 + r)*N + col0 + n*16] = (bf16_t)acc[m][n][r];
}

// ---------------- C = A (MxK, lda) * B^T (NxK packed), bf16 in, fp32 acc ----------------
// 128x128 tile, BK=64, 256 threads (4 waves, 2x2 of 64x64), mfma 16x16x32 bf16
// MODE: 0 = f32 C, 2 = fused dt/aBu epilogue (GEMM2)
template<int MODE>
__global__ void gemm_bt(const bf16_t* __restrict__ A, const bf16_t* __restrict__ B,
                        void* __restrict__ Cv, int lda, int N, int K,
                        const float* __restrict__ u_g, const float* __restrict__ b_dt_g,
                        const float* __restrict__ A_log_g)
{
  __shared__ __align__(16) bf16_t As[128*64];
  __shared__ __align__(16) bf16_t Bs[128*64];
  const int tid = threadIdx.x;
  const int l = tid & 63, w = tid >> 6;
  const int bm = blockIdx.x, bn = blockIdx.y;
  const bf16_t* Ab = A + (size_t)bm*128*lda;
  const bf16_t* Bb = B + (size_t)bn*128*K;
  f32x4 acc[4][4] = {};
  const int wr = (w>>1)*64, wc = (w&1)*64;
  const int lr = l & 15, lk = (l>>4)*8;
  const int srow = w*8 + (l>>3);
  const int scol = (l&7)*8;

  for (int kt = 0; kt < K; kt += 64) {
#pragma unroll
    for (int i = 0; i < 4; i++) {
      gload_lds16(Ab + (size_t)(i*32 + srow)*lda + kt + scol, As + i*2048 + w*512);
      gload_lds16(Bb + (size_t)(i*32 + srow)*K   + kt + scol, Bs + i*2048 + w*512);
    }
    __syncthreads();
#pragma unroll
    for (int kk = 0; kk < 2; kk++) {
      bf16x8 af[4], bv[4];
#pragma unroll
      for (int m = 0; m < 4; m++) af[m] = *(const bf16x8*)&As[(wr + m*16 + lr)*64 + kk*32 + lk];
#pragma unroll
      for (int n = 0; n < 4; n++) bv[n] = *(const bf16x8*)&Bs[(wc + n*16 + lr)*64 + kk*32 + lk];
#pragma unroll
      for (int m = 0; m < 4; m++)
#pragma unroll
        for (int n = 0; n < 4; n++)
          acc[m][n] = __builtin_amdgcn_mfma_f32_16x16x32_bf16(af[m], bv[n], acc[m][n], 0, 0, 0);
    }
    __syncthreads();
  }
  const int row0 = bm*128 + wr + (l>>4)*4;
  const int col0 = bn*128 + wc + lr;

  if constexpr (MODE == 2) {
    if (wc == 0) {
      const float bdt  = b_dt_g[lr];
      const float Aexp = expf(A_log_g[lr]);
      float2* aBu = (float2*)Cv;
#pragma unroll
      for (int m = 0; m < 4; m++)
#pragma unroll
        for (int r = 0; r < 4; r++) {
          int row = row0 + m*16 + r;
          float xdt = acc[m][0][r] + bdt;
          float dt  = (xdt > 20.f) ? xdt : log1pf(expf(xdt));
          float a   = expf(-Aexp * dt);
          float Bu  = dt * acc[m][1][r] * u_g[row];
          int b = row >> 12, li = row & 4095;
          aBu[(size_t)((b<<4) + lr)*4096 + li] = make_float2(a, Bu);
        }
    }
    return;
  }

#pragma unroll
  for (int m = 0; m < 4; m++)
#pragma unroll
    for (int n = 0; n < 4; n++)
#pragma unroll
      for (int r = 0; r < 4; r++) {
        size_t idx = (size_t)(row0 + m*16 + r)*N + (col0 + n*16);
        ((float*)Cv)[idx] = acc[m][n][r];
      }
}

// ---------------- fp32 -> bf16 conversions + packed W_dt/W_x[16:32] ----------------
__global__ __launch_bounds__(256) void convert_kernel(
    const float* __restrict__ x, const float* __restrict__ W_in,
    const float* __restrict__ W_out, const float* __restrict__ W_dt, const float* __restrict__ W_x,
    bf16_t* __restrict__ x_bf, bf16_t* __restrict__ Win_bf,
    bf16_t* __restrict__ Wout_bf, bf16_t* __restrict__ Wcat_bf)
{
  const size_t N0 = 8388608/4, N1 = N0 + 1048576/4, N2 = N1 + 524288/4, N3 = N2 + 131072/4;
  size_t i = (size_t)blockIdx.x*256 + threadIdx.x;
  bf16_t* dst; float4 v;
  if (i < N0)      { v = ((const float4*)x)[i];          dst = x_bf   + i*4; }
  else if (i < N1) { size_t j = i - N0; v = ((const float4*)W_in)[j];  dst = Win_bf  + j*4; }
  else if (i < N2) { size_t j = i - N1; v = ((const float4*)W_out)[j]; dst = Wout_bf + j*4; }
  else if (i < N3) {
    size_t j = i - N2; size_t el = j*4; int r = (int)(el >> 10), c = (int)(el & 1023);
    if (r < 16)      v = *(const float4*)(W_dt + r*1024 + c);
    else if (r < 32) v = *(const float4*)(W_x  + r*1024 + c);
    else             v = make_float4(0.f, 0.f, 0.f, 0.f);
    dst = Wcat_bf + el;
  } else return;
  bf16x4 o; o[0]=(bf16_t)v.x; o[1]=(bf16_t)v.y; o[2]=(bf16_t)v.z; o[3]=(bf16_t)v.w;
  *(bf16x4*)dst = o;
}

// ------------- depthwise causal conv(4) + bias + SiLU + u=mean(xa[:,:64]) -------------
#define CONV_R 4
__global__ __launch_bounds__(256) void conv_kernel(
    const bf16_t* __restrict__ xi_res, const float* __restrict__ conv_w,
    const float* __restrict__ conv_b, bf16_t* __restrict__ xa, float* __restrict__ u)
{
  const int team = blockIdx.x*2 + (threadIdx.x >> 7);   // 4096 teams
  const int t    = threadIdx.x & 127;
  const int b    = team >> 10;
  const int r0   = (team & 1023) * CONV_R;
  const int c0   = t * 8;

  float w[8][4], bias[8];
#pragma unroll
  for (int e = 0; e < 8; e++) {
    float4 v = *(const float4*)(conv_w + (size_t)(c0 + e)*4);
    w[e][0]=v.x; w[e][1]=v.y; w[e][2]=v.z; w[e][3]=v.w;
  }
  {
    float4 b0 = *(const float4*)(conv_b + c0);
    float4 b1 = *(const float4*)(conv_b + c0 + 4);
    bias[0]=b0.x; bias[1]=b0.y; bias[2]=b0.z; bias[3]=b0.w;
    bias[4]=b1.x; bias[5]=b1.y; bias[6]=b1.z; bias[7]=b1.w;
  }

  const bf16_t* xbase = xi_res + ((size_t)b*SEQ + r0)*2048 + c0;
  bf16x8 rowv[CONV_R + 3];
#pragma unroll
  for (int k = 0; k < 3; k++) {
#pragma unroll
    for (int e = 0; e < 8; e++) rowv[k][e] = (bf16_t)0.f;
    if (r0 - 3 + k >= 0) rowv[k] = *(const bf16x8*)(xbase + (k - 3)*2048);
  }
#pragma unroll
  for (int k = 0; k < CONV_R; k++)
    rowv[3 + k] = *(const bf16x8*)(xbase + k*2048);

  const int growbase = b*SEQ + r0;
#pragma unroll
  for (int i = 0; i < CONV_R; i++) {
    bf16x8 o;
    float usum = 0.f;
#pragma unroll
    for (int e = 0; e < 8; e++) {
      float acc = bias[e]
        + w[e][0]*(float)rowv[i  ][e]
        + w[e][1]*(float)rowv[i+1][e]
        + w[e][2]*(float)rowv[i+2][e]
        + w[e][3]*(float)rowv[i+3][e];
      float sil = acc / (1.f + expf(-acc));
      usum += sil;
      o[e] = (bf16_t)sil;
    }
    *(bf16x8*)(xa + (size_t)(growbase + i)*DIN + c0) = o;
    if (t < 8) {
      usum += __shfl_xor(usum, 1, 64);
      usum += __shfl_xor(usum, 2, 64);
      usum += __shfl_xor(usum, 4, 64);
      if (t == 0) u[growbase + i] = usum * (1.f/64.f);
    }
  }
}

// ---------------- segmented scan over L=4096 per (b,n): 256 threads, 16 steps each ----------------
__global__ __launch_bounds__(256) void scan_kernel(const float2* __restrict__ aBu, float* __restrict__ y)
{
  __shared__ float2 lds[4096 + 256];   // padded: phys(i) = i + i/16
  __shared__ float2 wtot[4];
  const int tid = threadIdx.x;
  const int bn = blockIdx.x;
  const float2* base = aBu + (size_t)bn*4096;

#pragma unroll
  for (int c = 0; c < 16; c++) {
    int i = c*256 + tid;
    lds[i + (i>>4)] = base[i];
  }
  __syncthreads();

  const int p0 = tid*17;
  float P = 1.f, S = 0.f;
#pragma unroll
  for (int j = 0; j < 16; j++) {
    float2 ab = lds[p0 + j];
    S = S*ab.x + ab.y;
    P *= ab.x;
  }
  float Pi = P, Si = S;
  const int l = tid & 63;
#pragma unroll
  for (int off = 1; off < 64; off <<= 1) {
    float Pp = __shfl_up(Pi, off, 64);
    float Sp = __shfl_up(Si, off, 64);
    if (l >= off) { Si = Sp*Pi + Si; Pi = Pp*Pi; }
  }
  const int w = tid >> 6;
  if (l == 63) wtot[w] = make_float2(Pi, Si);
  __syncthreads();

  float Sc = 0.f;
  for (int k = 0; k < 4; k++)
    if (k < w) { Sc = Sc*wtot[k].x + wtot[k].y; }
  float Pe = 1.f, Se = 0.f;
  {
    float Pp = __shfl_up(Pi, 1, 64);
    float Sp = __shfl_up(Si, 1, 64);
    if (l > 0) { Pe = Pp; Se = Sp; }
  }
  float s = Sc*Pe + Se;

#pragma unroll
  for (int j = 0; j < 16; j++) {
    float2 ab = lds[p0 + j];
    s = s*ab.x + ab.y;
    lds[p0 + j].x = s;
  }
  __syncthreads();
  float* yb = y + (size_t)bn*4096;
#pragma unroll
  for (int c = 0; c < 16; c++) {
    int i = c*256 + tid;
    yb[i] = lds[i + (i>>4)].x;
  }
}

// ---------------- y_full = (y_rep + xa*D) * silu(res) -> written into xi half of xi_res ----------------
__global__ __launch_bounds__(256) void yfull_kernel(
    const bf16_t* __restrict__ xa, bf16_t* __restrict__ xi_res,
    const float* __restrict__ y_state, const float* __restrict__ D_param)
{
  int idx = blockIdx.x*256 + threadIdx.x;
  int row = idx >> 7, cc = (idx & 127)*8;
  bf16x8 xav  = *(const bf16x8*)&xa[(size_t)row*DIN + cc];
  bf16x8 resv = *(const bf16x8*)&xi_res[(size_t)row*2048 + DIN + cc];
  int b = row >> 12, li = row & 4095, n = cc >> 6;
  float ys = y_state[(size_t)((b<<4) + n)*4096 + li];
  float dp[8];
  float4 d0 = *(const float4*)(D_param + cc);
  float4 d1 = *(const float4*)(D_param + cc + 4);
  dp[0]=d0.x; dp[1]=d0.y; dp[2]=d0.z; dp[3]=d0.w; dp[4]=d1.x; dp[5]=d1.y; dp[6]=d1.z; dp[7]=d1.w;
  bf16x8 o;
#pragma unroll
  for (int e = 0; e < 8; e++) {
    float r = (float)resv[e];
    float sil = r / (1.f + expf(-r));
    float yv = (ys + (float)xav[e]*dp[e]) * sil;
    o[e] = (bf16_t)yv;
  }
  *(bf16x8*)&xi_res[(size_t)row*2048 + cc] = o;
}

extern "C" void kernel_launch(void* const* d_in, const int* in_sizes, int n_in,
                              void* d_out, int out_size, void* d_ws, size_t ws_size,
                              hipStream_t stream)
{
  const float* x      = (const float*)d_in[0];
  const float* W_in   = (const float*)d_in[1];
  const float* conv_w = (const float*)d_in[2];
  const float* conv_b = (const float*)d_in[3];
  const float* W_x    = (const float*)d_in[4];
  const float* W_dt   = (const float*)d_in[5];
  const float* b_dt   = (const float*)d_in[6];
  const float* A_log  = (const float*)d_in[7];
  const float* D_param= (const float*)d_in[8];
  const float* W_out  = (const float*)d_in[9];
  float* out = (float*)d_out;
  char* ws = (char*)d_ws;

  if (ws_size < 121700352u) return;  // ~116 MB scratch

  const size_t MB = 1024*1024;
  bf16_t* x_bf    = (bf16_t*)(ws + 0);          // 16 MB, dead after gemm1
  float*  y_state = (float*) (ws + 8*MB);       //  1 MB, overlays x_bf upper half
  bf16_t* Win_bf  = (bf16_t*)(ws + 16*MB);      //  2 MB, dead after gemm1
  float2* aBu     = (float2*)(ws + 16*MB);      //  2 MB, overlays Win_bf
  bf16_t* Wout_bf = (bf16_t*)(ws + 18*MB);      //  1 MB
  bf16_t* Wcat_bf = (bf16_t*)(ws + 19*MB);      //  0.25 MB
  bf16_t* xi_res  = (bf16_t*)(ws + 20*MB);      // 64 MB (xi half reused as yfull)
  bf16_t* xa      = (bf16_t*)(ws + 84*MB);      // 32 MB
  float*  u       = (float*) (ws + 116*MB);     // 64 KB

  convert_kernel<<<dim3(9856), dim3(256), 0, stream>>>(x, W_in, W_out, W_dt, W_x,
                                                       x_bf, Win_bf, Wout_bf, Wcat_bf);
  gemm8<<<dim3(64, 8), dim3(512), 0, stream>>>(x_bf, Win_bf, xi_res, 512, 512, 2048, 512);
  conv_kernel<<<dim3(2048), dim3(256), 0, stream>>>(xi_res, conv_w, conv_b, xa, u);
  gemm_bt<2><<<dim3(128,1), dim3(256), 0, stream>>>(xa, Wcat_bf, (void*)aBu, 1024, 128, 1024,
                                                    u, b_dt, A_log);
  scan_kernel<<<dim3(64), dim3(256), 0, stream>>>(aBu, y_state);
  yfull_kernel<<<dim3(8192), dim3(256), 0, stream>>>(xa, xi_res, y_state, D_param);
  gemm_bt<0><<<dim3(128,4), dim3(256), 0, stream>>>(xi_res, Wout_bf, (void*)out, 2048, 512, 1024,
                                                    nullptr, nullptr, nullptr);
}

// Round 8
// 229.339 us; speedup vs baseline: 1.0430x; 1.0430x over previous
//
#include <hip/hip_runtime.h>
#include <stdint.h>

typedef __bf16 bf16_t;
typedef __bf16 bf16x8 __attribute__((ext_vector_type(8)));
typedef __bf16 bf16x4 __attribute__((ext_vector_type(4)));
typedef float  f32x4  __attribute__((ext_vector_type(4)));

#define AS1 __attribute__((address_space(1)))
#define AS3 __attribute__((address_space(3)))

#define SEQ   4096
#define DIMM  512
#define DIN   1024
#define ROWS  16384   // BATCH*SEQLEN

__device__ __forceinline__ void gload_lds16(const void* g, void* l) {
  __builtin_amdgcn_global_load_lds((AS1 void*)g, (AS3 void*)l, 16, 0, 0);
}

// ================= GEMM1: 256x256 tile, BK=32, 4-deep LDS ring, counted vmcnt =================
// C = A (MxK, lda) * B^T (NxK, ldb), bf16 in, bf16 out. 512 threads = 8 waves (2M x 4N).
// LDS kept linear for global_load_lds; bank-conflict-free via pre-swizzled GLOBAL slot:
//   LDS (row r, slot s) holds global slot s ^ ((r>>1)&3); reads XOR the same term.
//   Stage side: f = (tid>>3)&3 (row = tid>>2); read side: f = (lr>>1)&3 (row bases = 0 mod 16).
__global__ __launch_bounds__(512, 2) void gemm8(
    const bf16_t* __restrict__ A, const bf16_t* __restrict__ B,
    bf16_t* __restrict__ C, int lda, int ldb, int N, int K)
{
  __shared__ __align__(16) bf16_t Abuf[4][256*32];
  __shared__ __align__(16) bf16_t Bbuf[4][256*32];
  const int tid = threadIdx.x;
  const int l = tid & 63, w = tid >> 6;
  const int wr = w >> 2, wc = w & 3;          // wave's M-half / N-quarter
  const int lr = l & 15, g = l >> 4;          // frag row lane, k-granule
  const int bm = blockIdx.x, bn = blockIdx.y;
  const int NT = K >> 5;

  // staging: thread covers LDS (row = tid>>2, slot = tid&3); fetches global slot^f(row)
  const int r0  = tid >> 2;
  const int c0e = ((tid & 3) ^ ((tid >> 3) & 3)) * 8;
  const bf16_t* As0 = A + (size_t)(bm*256 +       r0)*lda + c0e;
  const bf16_t* As1 = A + (size_t)(bm*256 + 128 + r0)*lda + c0e;
  const bf16_t* Bs0 = B + (size_t)(bn*256 +       r0)*ldb + c0e;
  const bf16_t* Bs1 = B + (size_t)(bn*256 + 128 + r0)*ldb + c0e;

  f32x4 acc[8][4] = {};

#define STAGE_A(kt_) { int d_ = (kt_) & 3; size_t ko_ = (size_t)(kt_)*32; \
    gload_lds16(As0 + ko_, &Abuf[d_][w*512]); \
    gload_lds16(As1 + ko_, &Abuf[d_][4096 + w*512]); }
#define STAGE_B(kt_) { int d_ = (kt_) & 3; size_t ko_ = (size_t)(kt_)*32; \
    gload_lds16(Bs0 + ko_, &Bbuf[d_][w*512]); \
    gload_lds16(Bs1 + ko_, &Bbuf[d_][4096 + w*512]); }

  // prologue: stage kt0, kt1; wait for kt0 (oldest 4 of 8)
  STAGE_A(0); STAGE_B(0);
  STAGE_A(1); STAGE_B(1);
  asm volatile("s_waitcnt vmcnt(4)" ::: "memory");
  __builtin_amdgcn_s_barrier();
  __builtin_amdgcn_sched_barrier(0);

  const int arow = wr*128 + lr;   // + m*16 (+64 for phase 2)
  const int brow = wc*64  + lr;   // + n*16
  const int kcol = (g ^ ((lr >> 1) & 3)) * 8;   // swizzled k-slot (per-lane constant)

  for (int kt = 0; kt < NT; ++kt) {
    const bf16_t* Ab = Abuf[kt & 3];
    const bf16_t* Bb = Bbuf[kt & 3];
    bf16x8 av[4], bv[4];
    // ---- phase 1: rows 0..63 of wave's half ----
#pragma unroll
    for (int m = 0; m < 4; m++) av[m] = *(const bf16x8*)&Ab[(arow + m*16)*32 + kcol];
#pragma unroll
    for (int n = 0; n < 4; n++) bv[n] = *(const bf16x8*)&Bb[(brow + n*16)*32 + kcol];
    if (kt + 2 < NT) STAGE_A(kt + 2);
    asm volatile("s_waitcnt lgkmcnt(0)" ::: "memory");
    __builtin_amdgcn_sched_barrier(0);
    __builtin_amdgcn_s_setprio(1);
#pragma unroll
    for (int m = 0; m < 4; m++)
#pragma unroll
      for (int n = 0; n < 4; n++)
        acc[m][n] = __builtin_amdgcn_mfma_f32_16x16x32_bf16(av[m], bv[n], acc[m][n], 0, 0, 0);
    __builtin_amdgcn_s_setprio(0);
    __builtin_amdgcn_sched_barrier(0);
    // ---- phase 2: rows 64..127 (B frags reused from registers) ----
#pragma unroll
    for (int m = 0; m < 4; m++) av[m] = *(const bf16x8*)&Ab[(arow + 64 + m*16)*32 + kcol];
    if (kt + 2 < NT) STAGE_B(kt + 2);
    asm volatile("s_waitcnt lgkmcnt(0)" ::: "memory");
    __builtin_amdgcn_sched_barrier(0);
    __builtin_amdgcn_s_setprio(1);
#pragma unroll
    for (int m = 0; m < 4; m++)
#pragma unroll
      for (int n = 0; n < 4; n++)
        acc[4+m][n] = __builtin_amdgcn_mfma_f32_16x16x32_bf16(av[m], bv[n], acc[4+m][n], 0, 0, 0);
    __builtin_amdgcn_s_setprio(0);
    __builtin_amdgcn_sched_barrier(0);
    // ---- K-tile boundary: counted wait for next tile's 4 loads, then barrier ----
    if (kt < NT - 1) {
      if (kt + 2 < NT) asm volatile("s_waitcnt vmcnt(4)" ::: "memory");
      else             asm volatile("s_waitcnt vmcnt(0)" ::: "memory");
      __builtin_amdgcn_s_barrier();
      __builtin_amdgcn_sched_barrier(0);
    }
  }
#undef STAGE_A
#undef STAGE_B

  const int row0 = bm*256 + wr*128 + g*4;
  const int col0 = bn*256 + wc*64 + lr;
#pragma unroll
  for (int m = 0; m < 8; m++)
#pragma unroll
    for (int n = 0; n < 4; n++)
#pragma unroll
      for (int r = 0; r < 4; r++)
        C[(size_t)(row0 + m*16 + r)*N + col0 + n*16] = (bf16_t)acc[m][n][r];
}

// ---------------- C = A (MxK, lda) * B^T (NxK packed), bf16 in, fp32 acc ----------------
// 128x128 tile, BK=64, 256 threads (4 waves, 2x2 of 64x64), mfma 16x16x32 bf16
// MODE: 0 = f32 C, 2 = fused dt/aBu epilogue (GEMM2)
// LDS [128][64] linear; swizzled global slot: LDS (r, s) holds global slot s ^ (r&7).
template<int MODE>
__global__ void gemm_bt(const bf16_t* __restrict__ A, const bf16_t* __restrict__ B,
                        void* __restrict__ Cv, int lda, int N, int K,
                        const float* __restrict__ u_g, const float* __restrict__ b_dt_g,
                        const float* __restrict__ A_log_g)
{
  __shared__ __align__(16) bf16_t As[128*64];
  __shared__ __align__(16) bf16_t Bs[128*64];
  const int tid = threadIdx.x;
  const int l = tid & 63, w = tid >> 6;
  const int bm = blockIdx.x, bn = blockIdx.y;
  const bf16_t* Ab = A + (size_t)bm*128*lda;
  const bf16_t* Bb = B + (size_t)bn*128*K;
  f32x4 acc[4][4] = {};
  const int wr = (w>>1)*64, wc = (w&1)*64;
  const int lr = l & 15;
  const int srow = w*8 + (l>>3);                       // stage row within 32-row group
  const int scol = ((tid&7) ^ ((tid>>3)&7)) * 8;       // swizzled stage slot (row&7 = (tid>>3)&7)
  const int lk0  = ((l>>4) ^ (l&7)) * 8;               // read slot, kk=0 (row&7 = lr&7 = l&7)
  const int lk1  = lk0 ^ 32;                           // kk=1 flips slot bit 2

  for (int kt = 0; kt < K; kt += 64) {
#pragma unroll
    for (int i = 0; i < 4; i++) {
      gload_lds16(Ab + (size_t)(i*32 + srow)*lda + kt + scol, As + i*2048 + w*512);
      gload_lds16(Bb + (size_t)(i*32 + srow)*K   + kt + scol, Bs + i*2048 + w*512);
    }
    __syncthreads();
#pragma unroll
    for (int kk = 0; kk < 2; kk++) {
      const int lk = kk ? lk1 : lk0;
      bf16x8 af[4], bv[4];
#pragma unroll
      for (int m = 0; m < 4; m++) af[m] = *(const bf16x8*)&As[(wr + m*16 + lr)*64 + lk];
#pragma unroll
      for (int n = 0; n < 4; n++) bv[n] = *(const bf16x8*)&Bs[(wc + n*16 + lr)*64 + lk];
#pragma unroll
      for (int m = 0; m < 4; m++)
#pragma unroll
        for (int n = 0; n < 4; n++)
          acc[m][n] = __builtin_amdgcn_mfma_f32_16x16x32_bf16(af[m], bv[n], acc[m][n], 0, 0, 0);
    }
    __syncthreads();
  }
  const int row0 = bm*128 + wr + (l>>4)*4;
  const int col0 = bn*128 + wc + lr;

  if constexpr (MODE == 2) {
    if (wc == 0) {
      const float bdt  = b_dt_g[lr];
      const float Aexp = expf(A_log_g[lr]);
      float2* aBu = (float2*)Cv;
#pragma unroll
      for (int m = 0; m < 4; m++)
#pragma unroll
        for (int r = 0; r < 4; r++) {
          int row = row0 + m*16 + r;
          float xdt = acc[m][0][r] + bdt;
          float dt  = (xdt > 20.f) ? xdt : log1pf(expf(xdt));
          float a   = expf(-Aexp * dt);
          float Bu  = dt * acc[m][1][r] * u_g[row];
          int b = row >> 12, li = row & 4095;
          aBu[(size_t)((b<<4) + lr)*4096 + li] = make_float2(a, Bu);
        }
    }
    return;
  }

#pragma unroll
  for (int m = 0; m < 4; m++)
#pragma unroll
    for (int n = 0; n < 4; n++)
#pragma unroll
      for (int r = 0; r < 4; r++) {
        size_t idx = (size_t)(row0 + m*16 + r)*N + (col0 + n*16);
        ((float*)Cv)[idx] = acc[m][n][r];
      }
}

// ---------------- fp32 -> bf16 conversions + packed W_dt/W_x[16:32] ----------------
__global__ __launch_bounds__(256) void convert_kernel(
    const float* __restrict__ x, const float* __restrict__ W_in,
    const float* __restrict__ W_out, const float* __restrict__ W_dt, const float* __restrict__ W_x,
    bf16_t* __restrict__ x_bf, bf16_t* __restrict__ Win_bf,
    bf16_t* __restrict__ Wout_bf, bf16_t* __restrict__ Wcat_bf)
{
  const size_t N0 = 8388608/4, N1 = N0 + 1048576/4, N2 = N1 + 524288/4, N3 = N2 + 131072/4;
  size_t i = (size_t)blockIdx.x*256 + threadIdx.x;
  bf16_t* dst; float4 v;
  if (i < N0)      { v = ((const float4*)x)[i];          dst = x_bf   + i*4; }
  else if (i < N1) { size_t j = i - N0; v = ((const float4*)W_in)[j];  dst = Win_bf  + j*4; }
  else if (i < N2) { size_t j = i - N1; v = ((const float4*)W_out)[j]; dst = Wout_bf + j*4; }
  else if (i < N3) {
    size_t j = i - N2; size_t el = j*4; int r = (int)(el >> 10), c = (int)(el & 1023);
    if (r < 16)      v = *(const float4*)(W_dt + r*1024 + c);
    else if (r < 32) v = *(const float4*)(W_x  + r*1024 + c);
    else             v = make_float4(0.f, 0.f, 0.f, 0.f);
    dst = Wcat_bf + el;
  } else return;
  bf16x4 o; o[0]=(bf16_t)v.x; o[1]=(bf16_t)v.y; o[2]=(bf16_t)v.z; o[3]=(bf16_t)v.w;
  *(bf16x4*)dst = o;
}

// ------------- depthwise causal conv(4) + bias + SiLU + u=mean(xa[:,:64]) -------------
#define CONV_R 4
__global__ __launch_bounds__(256) void conv_kernel(
    const bf16_t* __restrict__ xi_res, const float* __restrict__ conv_w,
    const float* __restrict__ conv_b, bf16_t* __restrict__ xa, float* __restrict__ u)
{
  const int team = blockIdx.x*2 + (threadIdx.x >> 7);   // 4096 teams
  const int t    = threadIdx.x & 127;
  const int b    = team >> 10;
  const int r0   = (team & 1023) * CONV_R;
  const int c0   = t * 8;

  float w[8][4], bias[8];
#pragma unroll
  for (int e = 0; e < 8; e++) {
    float4 v = *(const float4*)(conv_w + (size_t)(c0 + e)*4);
    w[e][0]=v.x; w[e][1]=v.y; w[e][2]=v.z; w[e][3]=v.w;
  }
  {
    float4 b0 = *(const float4*)(conv_b + c0);
    float4 b1 = *(const float4*)(conv_b + c0 + 4);
    bias[0]=b0.x; bias[1]=b0.y; bias[2]=b0.z; bias[3]=b0.w;
    bias[4]=b1.x; bias[5]=b1.y; bias[6]=b1.z; bias[7]=b1.w;
  }

  const bf16_t* xbase = xi_res + ((size_t)b*SEQ + r0)*2048 + c0;
  bf16x8 rowv[CONV_R + 3];
#pragma unroll
  for (int k = 0; k < 3; k++) {
#pragma unroll
    for (int e = 0; e < 8; e++) rowv[k][e] = (bf16_t)0.f;
    if (r0 - 3 + k >= 0) rowv[k] = *(const bf16x8*)(xbase + (k - 3)*2048);
  }
#pragma unroll
  for (int k = 0; k < CONV_R; k++)
    rowv[3 + k] = *(const bf16x8*)(xbase + k*2048);

  const int growbase = b*SEQ + r0;
#pragma unroll
  for (int i = 0; i < CONV_R; i++) {
    bf16x8 o;
    float usum = 0.f;
#pragma unroll
    for (int e = 0; e < 8; e++) {
      float acc = bias[e]
        + w[e][0]*(float)rowv[i  ][e]
        + w[e][1]*(float)rowv[i+1][e]
        + w[e][2]*(float)rowv[i+2][e]
        + w[e][3]*(float)rowv[i+3][e];
      float sil = acc / (1.f + expf(-acc));
      usum += sil;
      o[e] = (bf16_t)sil;
    }
    *(bf16x8*)(xa + (size_t)(growbase + i)*DIN + c0) = o;
    if (t < 8) {
      usum += __shfl_xor(usum, 1, 64);
      usum += __shfl_xor(usum, 2, 64);
      usum += __shfl_xor(usum, 4, 64);
      if (t == 0) u[growbase + i] = usum * (1.f/64.f);
    }
  }
}

// ---------------- segmented scan over L=4096 per (b,n): 256 threads, 16 steps each ----------------
__global__ __launch_bounds__(256) void scan_kernel(const float2* __restrict__ aBu, float* __restrict__ y)
{
  __shared__ float2 lds[4096 + 256];   // padded: phys(i) = i + i/16
  __shared__ float2 wtot[4];
  const int tid = threadIdx.x;
  const int bn = blockIdx.x;
  const float2* base = aBu + (size_t)bn*4096;

#pragma unroll
  for (int c = 0; c < 16; c++) {
    int i = c*256 + tid;
    lds[i + (i>>4)] = base[i];
  }
  __syncthreads();

  const int p0 = tid*17;
  float P = 1.f, S = 0.f;
#pragma unroll
  for (int j = 0; j < 16; j++) {
    float2 ab = lds[p0 + j];
    S = S*ab.x + ab.y;
    P *= ab.x;
  }
  float Pi = P, Si = S;
  const int l = tid & 63;
#pragma unroll
  for (int off = 1; off < 64; off <<= 1) {
    float Pp = __shfl_up(Pi, off, 64);
    float Sp = __shfl_up(Si, off, 64);
    if (l >= off) { Si = Sp*Pi + Si; Pi = Pp*Pi; }
  }
  const int w = tid >> 6;
  if (l == 63) wtot[w] = make_float2(Pi, Si);
  __syncthreads();

  float Sc = 0.f;
  for (int k = 0; k < 4; k++)
    if (k < w) { Sc = Sc*wtot[k].x + wtot[k].y; }
  float Pe = 1.f, Se = 0.f;
  {
    float Pp = __shfl_up(Pi, 1, 64);
    float Sp = __shfl_up(Si, 1, 64);
    if (l > 0) { Pe = Pp; Se = Sp; }
  }
  float s = Sc*Pe + Se;

#pragma unroll
  for (int j = 0; j < 16; j++) {
    float2 ab = lds[p0 + j];
    s = s*ab.x + ab.y;
    lds[p0 + j].x = s;
  }
  __syncthreads();
  float* yb = y + (size_t)bn*4096;
#pragma unroll
  for (int c = 0; c < 16; c++) {
    int i = c*256 + tid;
    yb[i] = lds[i + (i>>4)].x;
  }
}

// ---------------- y_full = (y_rep + xa*D) * silu(res) -> written into xi half of xi_res ----------------
__global__ __launch_bounds__(256) void yfull_kernel(
    const bf16_t* __restrict__ xa, bf16_t* __restrict__ xi_res,
    const float* __restrict__ y_state, const float* __restrict__ D_param)
{
  int idx = blockIdx.x*256 + threadIdx.x;
  int row = idx >> 7, cc = (idx & 127)*8;
  bf16x8 xav  = *(const bf16x8*)&xa[(size_t)row*DIN + cc];
  bf16x8 resv = *(const bf16x8*)&xi_res[(size_t)row*2048 + DIN + cc];
  int b = row >> 12, li = row & 4095, n = cc >> 6;
  float ys = y_state[(size_t)((b<<4) + n)*4096 + li];
  float dp[8];
  float4 d0 = *(const float4*)(D_param + cc);
  float4 d1 = *(const float4*)(D_param + cc + 4);
  dp[0]=d0.x; dp[1]=d0.y; dp[2]=d0.z; dp[3]=d0.w; dp[4]=d1.x; dp[5]=d1.y; dp[6]=d1.z; dp[7]=d1.w;
  bf16x8 o;
#pragma unroll
  for (int e = 0; e < 8; e++) {
    float r = (float)resv[e];
    float sil = r / (1.f + expf(-r));
    float yv = (ys + (float)xav[e]*dp[e]) * sil;
    o[e] = (bf16_t)yv;
  }
  *(bf16x8*)&xi_res[(size_t)row*2048 + cc] = o;
}

extern "C" void kernel_launch(void* const* d_in, const int* in_sizes, int n_in,
                              void* d_out, int out_size, void* d_ws, size_t ws_size,
                              hipStream_t stream)
{
  const float* x      = (const float*)d_in[0];
  const float* W_in   = (const float*)d_in[1];
  const float* conv_w = (const float*)d_in[2];
  const float* conv_b = (const float*)d_in[3];
  const float* W_x    = (const float*)d_in[4];
  const float* W_dt   = (const float*)d_in[5];
  const float* b_dt   = (const float*)d_in[6];
  const float* A_log  = (const float*)d_in[7];
  const float* D_param= (const float*)d_in[8];
  const float* W_out  = (const float*)d_in[9];
  float* out = (float*)d_out;
  char* ws = (char*)d_ws;

  if (ws_size < 121700352u) return;  // ~116 MB scratch

  const size_t MB = 1024*1024;
  bf16_t* x_bf    = (bf16_t*)(ws + 0);          // 16 MB, dead after gemm1
  float*  y_state = (float*) (ws + 8*MB);       //  1 MB, overlays x_bf upper half
  bf16_t* Win_bf  = (bf16_t*)(ws + 16*MB);      //  2 MB, dead after gemm1
  float2* aBu     = (float2*)(ws + 16*MB);      //  2 MB, overlays Win_bf
  bf16_t* Wout_bf = (bf16_t*)(ws + 18*MB);      //  1 MB
  bf16_t* Wcat_bf = (bf16_t*)(ws + 19*MB);      //  0.25 MB
  bf16_t* xi_res  = (bf16_t*)(ws + 20*MB);      // 64 MB (xi half reused as yfull)
  bf16_t* xa      = (bf16_t*)(ws + 84*MB);      // 32 MB
  float*  u       = (float*) (ws + 116*MB);     // 64 KB

  convert_kernel<<<dim3(9856), dim3(256), 0, stream>>>(x, W_in, W_out, W_dt, W_x,
                                                       x_bf, Win_bf, Wout_bf, Wcat_bf);
  gemm8<<<dim3(64, 8), dim3(512), 0, stream>>>(x_bf, Win_bf, xi_res, 512, 512, 2048, 512);
  conv_kernel<<<dim3(2048), dim3(256), 0, stream>>>(xi_res, conv_w, conv_b, xa, u);
  gemm_bt<2><<<dim3(128,1), dim3(256), 0, stream>>>(xa, Wcat_bf, (void*)aBu, 1024, 128, 1024,
                                                    u, b_dt, A_log);
  scan_kernel<<<dim3(64), dim3(256), 0, stream>>>(aBu, y_state);
  yfull_kernel<<<dim3(8192), dim3(256), 0, stream>>>(xa, xi_res, y_state, D_param);
  gemm_bt<0><<<dim3(128,4), dim3(256), 0, stream>>>(xi_res, Wout_bf, (void*)out, 2048, 512, 1024,
                                                    nullptr, nullptr, nullptr);
}